// Round 8
// baseline (4253.378 us; speedup 1.0000x reference)
//
#include <hip/hip_runtime.h>
#include <hip/hip_cooperative_groups.h>
#include <stdint.h>

// MultiResolutionHashEncoding — R8: cooperative level-phased gather.
//
// R4 477us correct. R6 occupancy fix: no change -> fetch-throughput-bound.
// R7 two-phase level-outer: FETCH 1.53e6->1.03e6 KB, 442us total
//   (gather 351 @ 3.8TB/s effective, transpose 91 @ ~5.8TB/s roofline).
// R8: partial capture blamed on (a) block drift smearing 2-3 levels
//   concurrently (8-12MB working set > 4MB/XCD L2) and (b) ws write
//   stream allocating in L2 (2MB/XCD/level). Fixes: grid.sync() after
//   every level (cooperative, 2048 blocks = exact co-residency) +
//   nontemporal ws/coords accesses. Diagnostic: gather FETCH <= 0.5e6 KB.

#define TPB 256

typedef float vfloat4 __attribute__((ext_vector_type(4)));
typedef float vfloat2 __attribute__((ext_vector_type(2)));

__device__ __forceinline__ uint32_t hash_idx(float cx, float cy, float cz,
                                             int resi, int siz)
{
    const float rf = (float)resi;
    const int x = (int)floorf(cx * rf);
    const int y = (int)floorf(cy * rf);
    const int z = (int)floorf(cz * rf);
    // int32 wraparound multiplies + xor (uint32 = UB-free)
    const uint32_t h = (uint32_t)x * 73856093u
                     ^ (uint32_t)y * 19349663u
                     ^ (uint32_t)z * 83492791u;
    const int32_t hs = (int32_t)h;
    if (siz == (1 << 19)) {
        // numpy abs(INT_MIN)=INT_MIN; python-mod 2^19 == mask
        const uint32_t a = (hs < 0) ? (0u - h) : h;
        return a & 0x7FFFFu;
    } else {
        int32_t a = (hs < 0) ? (int32_t)(0u - h) : hs;
        int32_t r = a % siz;          // compile-time divisor -> magic mul
        if (r < 0) r += siz;
        return (uint32_t)r;
    }
}

#define RESI_LIST {16, 22, 30, 42, 58, 80, 111, 153, \
                   212, 294, 406, 561, 776, 1072, 1482, 2048}
#define SIZ_LIST  {4096, 10648, 27000, 74088, 195112, 512000, \
                   524288, 524288, 524288, 524288, 524288, \
                   524288, 524288, 524288, 524288, 524288}

// ------------- Phase 1 (cooperative): level-phased gather -> ws ------------
__global__ __launch_bounds__(TPB) void hashenc_gather_coop(
    const float* __restrict__ coords,
    const float* __restrict__ tables,
    float2* __restrict__ ws,
    int npts)
{
    constexpr int RESI[16] = RESI_LIST;
    constexpr int SIZ[16] = SIZ_LIST;

    cooperative_groups::grid_group grid = cooperative_groups::this_grid();

    const int t = threadIdx.x;
    const long long base = (long long)blockIdx.x * 1024;

    float cx[4], cy[4], cz[4];
#pragma unroll
    for (int j = 0; j < 4; ++j) {
        const long long p = base + j * 256 + t;
        cx[j] = __builtin_nontemporal_load(&coords[3 * p + 0]);
        cy[j] = __builtin_nontemporal_load(&coords[3 * p + 1]);
        cz[j] = __builtin_nontemporal_load(&coords[3 * p + 2]);
    }

#pragma unroll
    for (int l = 0; l < 16; ++l) {
        const float* tab = tables + ((size_t)l << 20);
        vfloat2 g[4];
#pragma unroll
        for (int j = 0; j < 4; ++j) {
            const uint32_t idx = hash_idx(cx[j], cy[j], cz[j], RESI[l], SIZ[l]);
            g[j] = *reinterpret_cast<const vfloat2*>(tab + ((size_t)idx << 1));
        }
        float2* wl = ws + (size_t)l * npts + base;
#pragma unroll
        for (int j = 0; j < 4; ++j)   // NT: don't evict the L2-hot table
            __builtin_nontemporal_store(g[j],
                reinterpret_cast<vfloat2*>(wl + j * 256 + t));
        // re-align all 2048 blocks so exactly one level's 4MB table is the
        // active working set per XCD L2
        grid.sync();
    }
}

// ------------- Phase 1 fallback (non-coop, R7 structure) -------------------
__global__ __launch_bounds__(TPB) void hashenc_gather(
    const float* __restrict__ coords,
    const float* __restrict__ tables,
    float2* __restrict__ ws,
    int npts)
{
    constexpr int RESI[16] = RESI_LIST;
    constexpr int SIZ[16] = SIZ_LIST;

    const int t = threadIdx.x;
    const long long base = (long long)blockIdx.x * 1024;

    float cx[4], cy[4], cz[4];
#pragma unroll
    for (int j = 0; j < 4; ++j) {
        const long long p = base + j * 256 + t;
        cx[j] = __builtin_nontemporal_load(&coords[3 * p + 0]);
        cy[j] = __builtin_nontemporal_load(&coords[3 * p + 1]);
        cz[j] = __builtin_nontemporal_load(&coords[3 * p + 2]);
    }

#pragma unroll
    for (int l = 0; l < 16; ++l) {
        const float* tab = tables + ((size_t)l << 20);
        vfloat2 g[4];
#pragma unroll
        for (int j = 0; j < 4; ++j) {
            const uint32_t idx = hash_idx(cx[j], cy[j], cz[j], RESI[l], SIZ[l]);
            g[j] = *reinterpret_cast<const vfloat2*>(tab + ((size_t)idx << 1));
        }
        float2* wl = ws + (size_t)l * npts + base;
#pragma unroll
        for (int j = 0; j < 4; ++j)
            __builtin_nontemporal_store(g[j],
                reinterpret_cast<vfloat2*>(wl + j * 256 + t));
    }
}

// ------------- Phase 2: transpose ws (L,N,2) -> out (N,32) -----------------
__global__ __launch_bounds__(TPB) void hashenc_transpose(
    const float2* __restrict__ ws,
    float* __restrict__ out,
    int npts)
{
    __shared__ float buf[128 * 33];

    const int t = threadIdx.x;
    const long long pbase = (long long)blockIdx.x * TPB;
    const long long p = pbase + t;

    vfloat2 feat[16];
#pragma unroll
    for (int l = 0; l < 16; ++l)
        feat[l] = __builtin_nontemporal_load(
            reinterpret_cast<const vfloat2*>(ws + (size_t)l * npts + p));

    float* oblk = out + pbase * 32;
#pragma unroll
    for (int h = 0; h < 2; ++h) {
        if ((t >> 7) == h) {
            const int r = t & 127;
#pragma unroll
            for (int l = 0; l < 16; ++l) {
                buf[r * 33 + 2 * l + 0] = feat[l].x;
                buf[r * 33 + 2 * l + 1] = feat[l].y;
            }
        }
        __syncthreads();
#pragma unroll
        for (int k = 0; k < 4; ++k) {
            const int f = k * 1024 + t * 4;
            const int row = f >> 5;
            const int col = f & 31;
            const vfloat4 v = *reinterpret_cast<const vfloat4*>(&buf[row * 33 + col]);
            __builtin_nontemporal_store(v,
                reinterpret_cast<vfloat4*>(&oblk[(long long)h * 4096 + f]));
        }
        __syncthreads();
    }
}

// ------------- Fallback: R6 single-phase (ws too small) --------------------
__global__ __launch_bounds__(TPB) void hashenc_kernel(
    const float* __restrict__ coords,
    const float* __restrict__ tables,
    float* __restrict__ out,
    int npts)
{
    constexpr int RESI[16] = RESI_LIST;
    constexpr int SIZ[16] = SIZ_LIST;

    __shared__ float buf[128 * 33];

    const int t = threadIdx.x;
    const long long pbase = (long long)blockIdx.x * TPB;
    const long long p = pbase + t;

    const float cx = coords[3 * p + 0];
    const float cy = coords[3 * p + 1];
    const float cz = coords[3 * p + 2];

    float2 feat[16];
#pragma unroll
    for (int l = 0; l < 16; ++l) {
        const uint32_t idx = hash_idx(cx, cy, cz, RESI[l], SIZ[l]);
        feat[l] = *reinterpret_cast<const float2*>(
            tables + ((size_t)l << 20) + ((size_t)idx << 1));
    }

    float* oblk = out + pbase * 32;
#pragma unroll
    for (int h = 0; h < 2; ++h) {
        if ((t >> 7) == h) {
            const int r = t & 127;
#pragma unroll
            for (int l = 0; l < 16; ++l) {
                buf[r * 33 + 2 * l + 0] = feat[l].x;
                buf[r * 33 + 2 * l + 1] = feat[l].y;
            }
        }
        __syncthreads();
#pragma unroll
        for (int k = 0; k < 4; ++k) {
            const int f = k * 1024 + t * 4;
            const int row = f >> 5;
            const int col = f & 31;
            const vfloat4 v = *reinterpret_cast<const vfloat4*>(&buf[row * 33 + col]);
            __builtin_nontemporal_store(v,
                reinterpret_cast<vfloat4*>(&oblk[(long long)h * 4096 + f]));
        }
        __syncthreads();
    }
}

extern "C" void kernel_launch(void* const* d_in, const int* in_sizes, int n_in,
                              void* d_out, int out_size, void* d_ws, size_t ws_size,
                              hipStream_t stream)
{
    const float* coords = (const float*)d_in[0];
    const float* tables = (const float*)d_in[1];
    float* out = (float*)d_out;
    const int npts = in_sizes[0] / 3;   // 2^21

    const size_t need = (size_t)16 * (size_t)npts * sizeof(float2);
    if (ws_size >= need && (npts % 1024) == 0) {
        float2* wsp = (float2*)d_ws;
        int n = npts;
        void* args[4] = {(void*)&coords, (void*)&tables, (void*)&wsp, (void*)&n};
        hipError_t err = hipLaunchCooperativeKernel(
            (const void*)hashenc_gather_coop,
            dim3(npts / 1024), dim3(TPB), args, 0, stream);
        if (err != hipSuccess) {
            // coop not available here (e.g. capture restriction): same math,
            // no grid sync — R7 behavior + NT stores.
            hipLaunchKernelGGL(hashenc_gather, dim3(npts / 1024), dim3(TPB),
                               0, stream, coords, tables, (float2*)d_ws, npts);
        }
        hipLaunchKernelGGL(hashenc_transpose, dim3(npts / TPB), dim3(TPB),
                           0, stream, (const float2*)d_ws, out, npts);
    } else {
        hipLaunchKernelGGL(hashenc_kernel, dim3(npts / TPB), dim3(TPB),
                           0, stream, coords, tables, out, npts);
    }
}

// Round 9
// 337.965 us; speedup vs baseline: 12.5853x; 12.5853x over previous
//
#include <hip/hip_runtime.h>
#include <stdint.h>

// MultiResolutionHashEncoding — R9: per-level kernel launches.
//
// R7: two-phase, gather FETCH 1.03e6 KB (drift smears levels), 442us.
// R8: coop grid.sync per level -> FETCH 0.23e6 KB (L2 capture CONFIRMED)
//   but grid.sync costs ~270us each (cross-XCD coherence flush + spin):
//   4389us. Right theory, wrong barrier.
// R9: kernel-launch boundaries as the barrier — 12 gather launches
//   (levels 0-4 grouped: tables sum 2.5MB < 4MB/XCD L2; levels 5..15
//   individually: 4MB each). Same-stream kernels serialize; graph replay
//   makes boundaries ~2-4us. Regular table/coords loads (cacheable),
//   NT ws stores. Phase-2 transpose unchanged (91us, streaming roofline).

#define TPB 256

typedef float vfloat4 __attribute__((ext_vector_type(4)));
typedef float vfloat2 __attribute__((ext_vector_type(2)));

__device__ __forceinline__ uint32_t hash_idx(float cx, float cy, float cz,
                                             int resi, int siz)
{
    const float rf = (float)resi;
    const int x = (int)floorf(cx * rf);
    const int y = (int)floorf(cy * rf);
    const int z = (int)floorf(cz * rf);
    const uint32_t h = (uint32_t)x * 73856093u
                     ^ (uint32_t)y * 19349663u
                     ^ (uint32_t)z * 83492791u;
    const int32_t hs = (int32_t)h;
    if (siz == (1 << 19)) {
        const uint32_t a = (hs < 0) ? (0u - h) : h;
        return a & 0x7FFFFu;
    } else {
        int32_t a = (hs < 0) ? (int32_t)(0u - h) : hs;
        int32_t r = a % siz;
        if (r < 0) r += siz;
        return (uint32_t)r;
    }
}

#define RESI_LIST {16, 22, 30, 42, 58, 80, 111, 153, \
                   212, 294, 406, 561, 776, 1072, 1482, 2048}
#define SIZ_LIST  {4096, 10648, 27000, 74088, 195112, 512000, \
                   524288, 524288, 524288, 524288, 524288, \
                   524288, 524288, 524288, 524288, 524288}

template<int L0, int L1>
__global__ __launch_bounds__(TPB) void hashenc_gather_lv(
    const float* __restrict__ coords,
    const float* __restrict__ tables,
    float2* __restrict__ ws,
    int npts)
{
    constexpr int RESI[16] = RESI_LIST;
    constexpr int SIZ[16] = SIZ_LIST;

    const int t = threadIdx.x;
    const long long base = (long long)blockIdx.x * 1024;

    float cx[4], cy[4], cz[4];
#pragma unroll
    for (int j = 0; j < 4; ++j) {
        const long long p = base + j * 256 + t;
        cx[j] = coords[3 * p + 0];
        cy[j] = coords[3 * p + 1];
        cz[j] = coords[3 * p + 2];
    }

#pragma unroll
    for (int l = L0; l < L1; ++l) {
        const float* tab = tables + ((size_t)l << 20);
        vfloat2 g[4];
#pragma unroll
        for (int j = 0; j < 4; ++j) {
            const uint32_t idx = hash_idx(cx[j], cy[j], cz[j], RESI[l], SIZ[l]);
            g[j] = *reinterpret_cast<const vfloat2*>(tab + ((size_t)idx << 1));
        }
        float2* wl = ws + (size_t)l * npts + base;
#pragma unroll
        for (int j = 0; j < 4; ++j)
            __builtin_nontemporal_store(g[j],
                reinterpret_cast<vfloat2*>(wl + j * 256 + t));
    }
}

__global__ __launch_bounds__(TPB) void hashenc_transpose(
    const float2* __restrict__ ws,
    float* __restrict__ out,
    int npts)
{
    __shared__ float buf[128 * 33];

    const int t = threadIdx.x;
    const long long pbase = (long long)blockIdx.x * TPB;
    const long long p = pbase + t;

    vfloat2 feat[16];
#pragma unroll
    for (int l = 0; l < 16; ++l)
        feat[l] = __builtin_nontemporal_load(
            reinterpret_cast<const vfloat2*>(ws + (size_t)l * npts + p));

    float* oblk = out + pbase * 32;
#pragma unroll
    for (int h = 0; h < 2; ++h) {
        if ((t >> 7) == h) {
            const int r = t & 127;
#pragma unroll
            for (int l = 0; l < 16; ++l) {
                buf[r * 33 + 2 * l + 0] = feat[l].x;
                buf[r * 33 + 2 * l + 1] = feat[l].y;
            }
        }
        __syncthreads();
#pragma unroll
        for (int k = 0; k < 4; ++k) {
            const int f = k * 1024 + t * 4;
            const int row = f >> 5;
            const int col = f & 31;
            const vfloat4 v = *reinterpret_cast<const vfloat4*>(&buf[row * 33 + col]);
            __builtin_nontemporal_store(v,
                reinterpret_cast<vfloat4*>(&oblk[(long long)h * 4096 + f]));
        }
        __syncthreads();
    }
}

__global__ __launch_bounds__(TPB) void hashenc_kernel(
    const float* __restrict__ coords,
    const float* __restrict__ tables,
    float* __restrict__ out,
    int npts)
{
    constexpr int RESI[16] = RESI_LIST;
    constexpr int SIZ[16] = SIZ_LIST;

    __shared__ float buf[128 * 33];

    const int t = threadIdx.x;
    const long long pbase = (long long)blockIdx.x * TPB;
    const long long p = pbase + t;

    const float cx = coords[3 * p + 0];
    const float cy = coords[3 * p + 1];
    const float cz = coords[3 * p + 2];

    float2 feat[16];
#pragma unroll
    for (int l = 0; l < 16; ++l) {
        const uint32_t idx = hash_idx(cx, cy, cz, RESI[l], SIZ[l]);
        feat[l] = *reinterpret_cast<const float2*>(
            tables + ((size_t)l << 20) + ((size_t)idx << 1));
    }

    float* oblk = out + pbase * 32;
#pragma unroll
    for (int h = 0; h < 2; ++h) {
        if ((t >> 7) == h) {
            const int r = t & 127;
#pragma unroll
            for (int l = 0; l < 16; ++l) {
                buf[r * 33 + 2 * l + 0] = feat[l].x;
                buf[r * 33 + 2 * l + 1] = feat[l].y;
            }
        }
        __syncthreads();
#pragma unroll
        for (int k = 0; k < 4; ++k) {
            const int f = k * 1024 + t * 4;
            const int row = f >> 5;
            const int col = f & 31;
            const vfloat4 v = *reinterpret_cast<const vfloat4*>(&buf[row * 33 + col]);
            __builtin_nontemporal_store(v,
                reinterpret_cast<vfloat4*>(&oblk[(long long)h * 4096 + f]));
        }
        __syncthreads();
    }
}

extern "C" void kernel_launch(void* const* d_in, const int* in_sizes, int n_in,
                              void* d_out, int out_size, void* d_ws, size_t ws_size,
                              hipStream_t stream)
{
    const float* coords = (const float*)d_in[0];
    const float* tables = (const float*)d_in[1];
    float* out = (float*)d_out;
    const int npts = in_sizes[0] / 3;   // 2^21

    const size_t need = (size_t)16 * (size_t)npts * sizeof(float2);
    if (ws_size >= need && (npts % 1024) == 0) {
        float2* ws = (float2*)d_ws;
        const dim3 g(npts / 1024), b(TPB);
        hipLaunchKernelGGL((hashenc_gather_lv<0, 5>),   g, b, 0, stream, coords, tables, ws, npts);
        hipLaunchKernelGGL((hashenc_gather_lv<5, 6>),   g, b, 0, stream, coords, tables, ws, npts);
        hipLaunchKernelGGL((hashenc_gather_lv<6, 7>),   g, b, 0, stream, coords, tables, ws, npts);
        hipLaunchKernelGGL((hashenc_gather_lv<7, 8>),   g, b, 0, stream, coords, tables, ws, npts);
        hipLaunchKernelGGL((hashenc_gather_lv<8, 9>),   g, b, 0, stream, coords, tables, ws, npts);
        hipLaunchKernelGGL((hashenc_gather_lv<9, 10>),  g, b, 0, stream, coords, tables, ws, npts);
        hipLaunchKernelGGL((hashenc_gather_lv<10, 11>), g, b, 0, stream, coords, tables, ws, npts);
        hipLaunchKernelGGL((hashenc_gather_lv<11, 12>), g, b, 0, stream, coords, tables, ws, npts);
        hipLaunchKernelGGL((hashenc_gather_lv<12, 13>), g, b, 0, stream, coords, tables, ws, npts);
        hipLaunchKernelGGL((hashenc_gather_lv<13, 14>), g, b, 0, stream, coords, tables, ws, npts);
        hipLaunchKernelGGL((hashenc_gather_lv<14, 15>), g, b, 0, stream, coords, tables, ws, npts);
        hipLaunchKernelGGL((hashenc_gather_lv<15, 16>), g, b, 0, stream, coords, tables, ws, npts);
        hipLaunchKernelGGL(hashenc_transpose, dim3(npts / TPB), b, 0, stream,
                           (const float2*)d_ws, out, npts);
    } else {
        hipLaunchKernelGGL(hashenc_kernel, dim3(npts / TPB), dim3(TPB), 0, stream,
                           coords, tables, out, npts);
    }
}

// Round 10
// 326.973 us; speedup vs baseline: 13.0083x; 1.0336x over previous
//
#include <hip/hip_runtime.h>
#include <stdint.h>

// MultiResolutionHashEncoding — R10: fat gathers + coarse levels fused
// into transpose.
//
// R7 free-run two-phase: 442us (gather FETCH 1.03e6 KB, drift).
// R8 coop grid.sync: FETCH 0.23e6 (L2 capture confirmed) but sync ~270us ea.
// R9 per-level launches: 338us (gather ~20us/launch x12 + transpose 91us).
//   Per-launch traffic is small -> launches are ramp/latency-bound, not BW.
// R10: (a) 8 pts/thread (was 4) -> 2x gather MLP, half the ramp per work;
//   (b) levels 0-4 (tables 2.47MB, always-L2-hot, no phasing needed) are
//   gathered inline in the transpose kernel -> -168MB ws round trip,
//   11 gather launches instead of 12.

#define TPB 256

typedef float vfloat4 __attribute__((ext_vector_type(4)));
typedef float vfloat2 __attribute__((ext_vector_type(2)));

__device__ __forceinline__ uint32_t hash_idx(float cx, float cy, float cz,
                                             int resi, int siz)
{
    const float rf = (float)resi;
    const int x = (int)floorf(cx * rf);
    const int y = (int)floorf(cy * rf);
    const int z = (int)floorf(cz * rf);
    // int32 wraparound multiplies + xor (uint32 = UB-free)
    const uint32_t h = (uint32_t)x * 73856093u
                     ^ (uint32_t)y * 19349663u
                     ^ (uint32_t)z * 83492791u;
    const int32_t hs = (int32_t)h;
    if (siz == (1 << 19)) {
        // numpy abs(INT_MIN)=INT_MIN; python-mod 2^19 == mask
        const uint32_t a = (hs < 0) ? (0u - h) : h;
        return a & 0x7FFFFu;
    } else {
        int32_t a = (hs < 0) ? (int32_t)(0u - h) : hs;
        int32_t r = a % siz;          // compile-time divisor -> magic mul
        if (r < 0) r += siz;
        return (uint32_t)r;
    }
}

#define RESI_LIST {16, 22, 30, 42, 58, 80, 111, 153, \
                   212, 294, 406, 561, 776, 1072, 1482, 2048}
#define SIZ_LIST  {4096, 10648, 27000, 74088, 195112, 512000, \
                   524288, 524288, 524288, 524288, 524288, \
                   524288, 524288, 524288, 524288, 524288}

// ---- Phase 1: one launch per fine level (5..15); boundary = barrier. ------
// ws holds ONLY fine levels: ws[(l-5)*npts + p], 11*N*8B = 176MB.
template<int LV>
__global__ __launch_bounds__(TPB) void hashenc_gather_lv(
    const float* __restrict__ coords,
    const float* __restrict__ tables,
    float2* __restrict__ ws,
    int npts)
{
    constexpr int RESI[16] = RESI_LIST;
    constexpr int SIZ[16] = SIZ_LIST;

    const int t = threadIdx.x;
    const long long base = (long long)blockIdx.x * 2048;
    const float* tab = tables + ((size_t)LV << 20);

    // 8 points/thread: 8 independent gathers in flight (was 4)
    vfloat2 g[8];
#pragma unroll
    for (int j = 0; j < 8; ++j) {
        const long long p = base + j * 256 + t;
        const float cx = coords[3 * p + 0];
        const float cy = coords[3 * p + 1];
        const float cz = coords[3 * p + 2];
        const uint32_t idx = hash_idx(cx, cy, cz, RESI[LV], SIZ[LV]);
        g[j] = *reinterpret_cast<const vfloat2*>(tab + ((size_t)idx << 1));
    }
    float2* wl = ws + (size_t)(LV - 5) * npts + base;
#pragma unroll
    for (int j = 0; j < 8; ++j)   // NT: don't evict the L2-hot table
        __builtin_nontemporal_store(g[j],
            reinterpret_cast<vfloat2*>(wl + j * 256 + t));
}

// ---- Phase 2: coarse gather (levels 0-4, tables 2.47MB = always L2-hot)
//      + transpose ws fine levels -> out (N,32) ----------------------------
__global__ __launch_bounds__(TPB) void hashenc_transpose_fused(
    const float* __restrict__ coords,
    const float* __restrict__ tables,
    const float2* __restrict__ ws,
    float* __restrict__ out,
    int npts)
{
    constexpr int RESI[16] = RESI_LIST;
    constexpr int SIZ[16] = SIZ_LIST;

    __shared__ float buf[128 * 33];

    const int t = threadIdx.x;
    const long long pbase = (long long)blockIdx.x * TPB;
    const long long p = pbase + t;

    const float cx = coords[3 * p + 0];
    const float cy = coords[3 * p + 1];
    const float cz = coords[3 * p + 2];

    vfloat2 feat[16];
#pragma unroll
    for (int l = 0; l < 5; ++l) {   // inline coarse gathers (hot tables)
        const uint32_t idx = hash_idx(cx, cy, cz, RESI[l], SIZ[l]);
        feat[l] = *reinterpret_cast<const vfloat2*>(
            tables + ((size_t)l << 20) + ((size_t)idx << 1));
    }
#pragma unroll
    for (int l = 5; l < 16; ++l)    // fine levels from ws (NT streaming)
        feat[l] = __builtin_nontemporal_load(
            reinterpret_cast<const vfloat2*>(ws + (size_t)(l - 5) * npts + p));

    float* oblk = out + pbase * 32;
#pragma unroll
    for (int h = 0; h < 2; ++h) {
        if ((t >> 7) == h) {
            const int r = t & 127;
#pragma unroll
            for (int l = 0; l < 16; ++l) {
                buf[r * 33 + 2 * l + 0] = feat[l].x;
                buf[r * 33 + 2 * l + 1] = feat[l].y;
            }
        }
        __syncthreads();
#pragma unroll
        for (int k = 0; k < 4; ++k) {
            const int f = k * 1024 + t * 4;
            const int row = f >> 5;
            const int col = f & 31;
            const vfloat4 v = *reinterpret_cast<const vfloat4*>(&buf[row * 33 + col]);
            __builtin_nontemporal_store(v,
                reinterpret_cast<vfloat4*>(&oblk[(long long)h * 4096 + f]));
        }
        __syncthreads();
    }
}

// ---- Fallback: R6 single-phase (ws too small / odd N) ---------------------
__global__ __launch_bounds__(TPB) void hashenc_kernel(
    const float* __restrict__ coords,
    const float* __restrict__ tables,
    float* __restrict__ out,
    int npts)
{
    constexpr int RESI[16] = RESI_LIST;
    constexpr int SIZ[16] = SIZ_LIST;

    __shared__ float buf[128 * 33];

    const int t = threadIdx.x;
    const long long pbase = (long long)blockIdx.x * TPB;
    const long long p = pbase + t;

    const float cx = coords[3 * p + 0];
    const float cy = coords[3 * p + 1];
    const float cz = coords[3 * p + 2];

    float2 feat[16];
#pragma unroll
    for (int l = 0; l < 16; ++l) {
        const uint32_t idx = hash_idx(cx, cy, cz, RESI[l], SIZ[l]);
        feat[l] = *reinterpret_cast<const float2*>(
            tables + ((size_t)l << 20) + ((size_t)idx << 1));
    }

    float* oblk = out + pbase * 32;
#pragma unroll
    for (int h = 0; h < 2; ++h) {
        if ((t >> 7) == h) {
            const int r = t & 127;
#pragma unroll
            for (int l = 0; l < 16; ++l) {
                buf[r * 33 + 2 * l + 0] = feat[l].x;
                buf[r * 33 + 2 * l + 1] = feat[l].y;
            }
        }
        __syncthreads();
#pragma unroll
        for (int k = 0; k < 4; ++k) {
            const int f = k * 1024 + t * 4;
            const int row = f >> 5;
            const int col = f & 31;
            const vfloat4 v = *reinterpret_cast<const vfloat4*>(&buf[row * 33 + col]);
            __builtin_nontemporal_store(v,
                reinterpret_cast<vfloat4*>(&oblk[(long long)h * 4096 + f]));
        }
        __syncthreads();
    }
}

extern "C" void kernel_launch(void* const* d_in, const int* in_sizes, int n_in,
                              void* d_out, int out_size, void* d_ws, size_t ws_size,
                              hipStream_t stream)
{
    const float* coords = (const float*)d_in[0];
    const float* tables = (const float*)d_in[1];
    float* out = (float*)d_out;
    const int npts = in_sizes[0] / 3;   // 2^21

    const size_t need = (size_t)11 * (size_t)npts * sizeof(float2);
    if (ws_size >= need && (npts % 2048) == 0) {
        float2* ws = (float2*)d_ws;
        const dim3 g(npts / 2048), b(TPB);
        hipLaunchKernelGGL((hashenc_gather_lv<5>),  g, b, 0, stream, coords, tables, ws, npts);
        hipLaunchKernelGGL((hashenc_gather_lv<6>),  g, b, 0, stream, coords, tables, ws, npts);
        hipLaunchKernelGGL((hashenc_gather_lv<7>),  g, b, 0, stream, coords, tables, ws, npts);
        hipLaunchKernelGGL((hashenc_gather_lv<8>),  g, b, 0, stream, coords, tables, ws, npts);
        hipLaunchKernelGGL((hashenc_gather_lv<9>),  g, b, 0, stream, coords, tables, ws, npts);
        hipLaunchKernelGGL((hashenc_gather_lv<10>), g, b, 0, stream, coords, tables, ws, npts);
        hipLaunchKernelGGL((hashenc_gather_lv<11>), g, b, 0, stream, coords, tables, ws, npts);
        hipLaunchKernelGGL((hashenc_gather_lv<12>), g, b, 0, stream, coords, tables, ws, npts);
        hipLaunchKernelGGL((hashenc_gather_lv<13>), g, b, 0, stream, coords, tables, ws, npts);
        hipLaunchKernelGGL((hashenc_gather_lv<14>), g, b, 0, stream, coords, tables, ws, npts);
        hipLaunchKernelGGL((hashenc_gather_lv<15>), g, b, 0, stream, coords, tables, ws, npts);
        hipLaunchKernelGGL(hashenc_transpose_fused, dim3(npts / TPB), b, 0, stream,
                           coords, tables, (const float2*)d_ws, out, npts);
    } else {
        hipLaunchKernelGGL(hashenc_kernel, dim3(npts / TPB), dim3(TPB), 0, stream,
                           coords, tables, out, npts);
    }
}

// Round 12
// 304.139 us; speedup vs baseline: 13.9850x; 1.0751x over previous
//
#include <hip/hip_runtime.h>
#include <stdint.h>

// MultiResolutionHashEncoding — R12: R11 pairing with the level-5 size
// bug fixed.
//
// R11 FAILED absmax=0.0999 (one level fully wrong): pair kernel masked
//   ALL fine levels with &0x7FFFF, but level 5's table is 512000=80^3,
//   not 2^19. Fix: compile-time gather_body<LV> per parity side (uses
//   hash_idx with SIZ[LV]); parity branch is wave-uniform.
// R11 theory (still untested): bid%8 XCD round-robin -> even bids on
//   XCDs{0,2,4,6}, odd on {1,3,5,7}; level-A/even level-B/odd keeps one
//   4MB table per XCD L2 while halving launch count (11->6).
// Diagnostic: gather FETCH 0.2-0.35e6 KB = capture held; >=0.6e6 = parity
//   assumption wrong.

#define TPB 256

typedef float vfloat4 __attribute__((ext_vector_type(4)));
typedef float vfloat2 __attribute__((ext_vector_type(2)));

__device__ __forceinline__ uint32_t hash_idx(float cx, float cy, float cz,
                                             int resi, int siz)
{
    const float rf = (float)resi;
    const int x = (int)floorf(cx * rf);
    const int y = (int)floorf(cy * rf);
    const int z = (int)floorf(cz * rf);
    // int32 wraparound multiplies + xor (uint32 = UB-free)
    const uint32_t h = (uint32_t)x * 73856093u
                     ^ (uint32_t)y * 19349663u
                     ^ (uint32_t)z * 83492791u;
    const int32_t hs = (int32_t)h;
    if (siz == (1 << 19)) {
        // numpy abs(INT_MIN)=INT_MIN; python-mod 2^19 == mask
        const uint32_t a = (hs < 0) ? (0u - h) : h;
        return a & 0x7FFFFu;
    } else {
        int32_t a = (hs < 0) ? (int32_t)(0u - h) : hs;
        int32_t r = a % siz;          // compile-time divisor -> magic mul
        if (r < 0) r += siz;
        return (uint32_t)r;
    }
}

#define RESI_LIST {16, 22, 30, 42, 58, 80, 111, 153, \
                   212, 294, 406, 561, 776, 1072, 1482, 2048}
#define SIZ_LIST  {4096, 10648, 27000, 74088, 195112, 512000, \
                   524288, 524288, 524288, 524288, 524288, \
                   524288, 524288, 524288, 524288, 524288}

// ---- compile-time per-level gather body (8 pts/thread) --------------------
template<int LV>
__device__ __forceinline__ void gather_body(
    const float* __restrict__ coords,
    const float* __restrict__ tables,
    float2* __restrict__ ws,
    int npts, long long bid2, int t)
{
    constexpr int RESI[16] = RESI_LIST;
    constexpr int SIZ[16] = SIZ_LIST;

    const long long base = bid2 * 2048;
    const float* tab = tables + ((size_t)LV << 20);

    vfloat2 g[8];
#pragma unroll
    for (int j = 0; j < 8; ++j) {
        const long long p = base + j * 256 + t;
        const float cx = coords[3 * p + 0];
        const float cy = coords[3 * p + 1];
        const float cz = coords[3 * p + 2];
        const uint32_t idx = hash_idx(cx, cy, cz, RESI[LV], SIZ[LV]);
        g[j] = *reinterpret_cast<const vfloat2*>(tab + ((size_t)idx << 1));
    }
    float2* wl = ws + (size_t)(LV - 5) * npts + base;
#pragma unroll
    for (int j = 0; j < 8; ++j)   // NT: don't evict the L2-hot table
        __builtin_nontemporal_store(g[j],
            reinterpret_cast<vfloat2*>(wl + j * 256 + t));
}

// ---- Phase 1a: paired fine levels; even bid -> LA, odd bid -> LB. ---------
// bid%8 XCD round-robin: each XCD L2 caches exactly one 4MB table.
template<int LA, int LB>
__global__ __launch_bounds__(TPB) void hashenc_gather_pair(
    const float* __restrict__ coords,
    const float* __restrict__ tables,
    float2* __restrict__ ws,
    int npts)
{
    const int t = threadIdx.x;
    const long long bid2 = blockIdx.x >> 1;
    if (blockIdx.x & 1)   // wave-uniform branch, both sides compile-time
        gather_body<LB>(coords, tables, ws, npts, bid2, t);
    else
        gather_body<LA>(coords, tables, ws, npts, bid2, t);
}

// ---- Phase 1b: single fine level (tail) -----------------------------------
template<int LV>
__global__ __launch_bounds__(TPB) void hashenc_gather_lv(
    const float* __restrict__ coords,
    const float* __restrict__ tables,
    float2* __restrict__ ws,
    int npts)
{
    gather_body<LV>(coords, tables, ws, npts, (long long)blockIdx.x, threadIdx.x);
}

// ---- Phase 2: coarse gather (levels 0-4, tables 2.47MB = L2-hot)
//      + transpose ws fine levels -> out (N,32) ----------------------------
__global__ __launch_bounds__(TPB) void hashenc_transpose_fused(
    const float* __restrict__ coords,
    const float* __restrict__ tables,
    const float2* __restrict__ ws,
    float* __restrict__ out,
    int npts)
{
    constexpr int RESI[16] = RESI_LIST;
    constexpr int SIZ[16] = SIZ_LIST;

    __shared__ float buf[128 * 33];

    const int t = threadIdx.x;
    const long long pbase = (long long)blockIdx.x * TPB;
    const long long p = pbase + t;

    const float cx = coords[3 * p + 0];
    const float cy = coords[3 * p + 1];
    const float cz = coords[3 * p + 2];

    vfloat2 feat[16];
#pragma unroll
    for (int l = 0; l < 5; ++l) {   // inline coarse gathers (hot tables)
        const uint32_t idx = hash_idx(cx, cy, cz, RESI[l], SIZ[l]);
        feat[l] = *reinterpret_cast<const vfloat2*>(
            tables + ((size_t)l << 20) + ((size_t)idx << 1));
    }
#pragma unroll
    for (int l = 5; l < 16; ++l)    // fine levels from ws (NT streaming)
        feat[l] = __builtin_nontemporal_load(
            reinterpret_cast<const vfloat2*>(ws + (size_t)(l - 5) * npts + p));

    float* oblk = out + pbase * 32;
#pragma unroll
    for (int h = 0; h < 2; ++h) {
        if ((t >> 7) == h) {
            const int r = t & 127;
#pragma unroll
            for (int l = 0; l < 16; ++l) {
                buf[r * 33 + 2 * l + 0] = feat[l].x;
                buf[r * 33 + 2 * l + 1] = feat[l].y;
            }
        }
        __syncthreads();
#pragma unroll
        for (int k = 0; k < 4; ++k) {
            const int f = k * 1024 + t * 4;
            const int row = f >> 5;
            const int col = f & 31;
            const vfloat4 v = *reinterpret_cast<const vfloat4*>(&buf[row * 33 + col]);
            __builtin_nontemporal_store(v,
                reinterpret_cast<vfloat4*>(&oblk[(long long)h * 4096 + f]));
        }
        __syncthreads();
    }
}

// ---- Fallback: R6 single-phase (ws too small / odd N) ---------------------
__global__ __launch_bounds__(TPB) void hashenc_kernel(
    const float* __restrict__ coords,
    const float* __restrict__ tables,
    float* __restrict__ out,
    int npts)
{
    constexpr int RESI[16] = RESI_LIST;
    constexpr int SIZ[16] = SIZ_LIST;

    __shared__ float buf[128 * 33];

    const int t = threadIdx.x;
    const long long pbase = (long long)blockIdx.x * TPB;
    const long long p = pbase + t;

    const float cx = coords[3 * p + 0];
    const float cy = coords[3 * p + 1];
    const float cz = coords[3 * p + 2];

    float2 feat[16];
#pragma unroll
    for (int l = 0; l < 16; ++l) {
        const uint32_t idx = hash_idx(cx, cy, cz, RESI[l], SIZ[l]);
        feat[l] = *reinterpret_cast<const float2*>(
            tables + ((size_t)l << 20) + ((size_t)idx << 1));
    }

    float* oblk = out + pbase * 32;
#pragma unroll
    for (int h = 0; h < 2; ++h) {
        if ((t >> 7) == h) {
            const int r = t & 127;
#pragma unroll
            for (int l = 0; l < 16; ++l) {
                buf[r * 33 + 2 * l + 0] = feat[l].x;
                buf[r * 33 + 2 * l + 1] = feat[l].y;
            }
        }
        __syncthreads();
#pragma unroll
        for (int k = 0; k < 4; ++k) {
            const int f = k * 1024 + t * 4;
            const int row = f >> 5;
            const int col = f & 31;
            const vfloat4 v = *reinterpret_cast<const vfloat4*>(&buf[row * 33 + col]);
            __builtin_nontemporal_store(v,
                reinterpret_cast<vfloat4*>(&oblk[(long long)h * 4096 + f]));
        }
        __syncthreads();
    }
}

extern "C" void kernel_launch(void* const* d_in, const int* in_sizes, int n_in,
                              void* d_out, int out_size, void* d_ws, size_t ws_size,
                              hipStream_t stream)
{
    const float* coords = (const float*)d_in[0];
    const float* tables = (const float*)d_in[1];
    float* out = (float*)d_out;
    const int npts = in_sizes[0] / 3;   // 2^21

    const size_t need = (size_t)11 * (size_t)npts * sizeof(float2);
    if (ws_size >= need && (npts % 2048) == 0) {
        float2* ws = (float2*)d_ws;
        const dim3 gp(npts / 1024), g1(npts / 2048), b(TPB);
        // paired launches: even bid -> first level (XCDs 0,2,4,6),
        // odd bid -> second level (XCDs 1,3,5,7). One 4MB table per XCD L2.
        hipLaunchKernelGGL((hashenc_gather_pair<5, 6>),   gp, b, 0, stream, coords, tables, ws, npts);
        hipLaunchKernelGGL((hashenc_gather_pair<7, 8>),   gp, b, 0, stream, coords, tables, ws, npts);
        hipLaunchKernelGGL((hashenc_gather_pair<9, 10>),  gp, b, 0, stream, coords, tables, ws, npts);
        hipLaunchKernelGGL((hashenc_gather_pair<11, 12>), gp, b, 0, stream, coords, tables, ws, npts);
        hipLaunchKernelGGL((hashenc_gather_pair<13, 14>), gp, b, 0, stream, coords, tables, ws, npts);
        hipLaunchKernelGGL((hashenc_gather_lv<15>),       g1, b, 0, stream, coords, tables, ws, npts);
        hipLaunchKernelGGL(hashenc_transpose_fused, dim3(npts / TPB), b, 0, stream,
                           coords, tables, (const float2*)d_ws, out, npts);
    } else {
        hipLaunchKernelGGL(hashenc_kernel, dim3(npts / TPB), dim3(TPB), 0, stream,
                           coords, tables, out, npts);
    }
}

// Round 13
// 298.809 us; speedup vs baseline: 14.2344x; 1.0178x over previous
//
#include <hip/hip_runtime.h>
#include <stdint.h>

// MultiResolutionHashEncoding — R13: one-level-per-XCD gather (2 launches).
//
// R12 paired launches: 304us = transpose ~95 + gathers ~209. Pairing saved
//   only 23us -> launch overhead small; gathers are L2-request-rate bound
//   (~512K line-req/XCD/launch in 18.8us ~= 11 lines/cyc). But 6 launches
//   mean XCDs serve requests only ~55% of gather time (ramps/fills/drains).
// R13: bid%8 -> XCD round-robin. Launch A: level 5+c on XCD class c —
//   each XCD owns ONE 4MB table (L2-resident, NO phasing/alignment needed;
//   cross-XCD drift harmless). Launch B: levels 13,14,15 spread {3,3,2}
//   over classes. Table fills 176->64MB, ramps 6->2, continuous service.
// Diagnostic: launch A in top-5 with FETCH ~0.5-0.9e5 KB = residency held;
//   total >350us + FETCH balloon = bid%8 assumption wrong, revert R12.

#define TPB 256

typedef float vfloat4 __attribute__((ext_vector_type(4)));
typedef float vfloat2 __attribute__((ext_vector_type(2)));

__device__ __forceinline__ uint32_t hash_idx(float cx, float cy, float cz,
                                             int resi, int siz)
{
    const float rf = (float)resi;
    const int x = (int)floorf(cx * rf);
    const int y = (int)floorf(cy * rf);
    const int z = (int)floorf(cz * rf);
    // int32 wraparound multiplies + xor (uint32 = UB-free)
    const uint32_t h = (uint32_t)x * 73856093u
                     ^ (uint32_t)y * 19349663u
                     ^ (uint32_t)z * 83492791u;
    const int32_t hs = (int32_t)h;
    if (siz == (1 << 19)) {
        // numpy abs(INT_MIN)=INT_MIN; python-mod 2^19 == mask
        const uint32_t a = (hs < 0) ? (0u - h) : h;
        return a & 0x7FFFFu;
    } else {
        int32_t a = (hs < 0) ? (int32_t)(0u - h) : hs;
        int32_t r = a % siz;          // compile-time divisor -> magic mul
        if (r < 0) r += siz;
        return (uint32_t)r;
    }
}

#define RESI_LIST {16, 22, 30, 42, 58, 80, 111, 153, \
                   212, 294, 406, 561, 776, 1072, 1482, 2048}
#define SIZ_LIST  {4096, 10648, 27000, 74088, 195112, 512000, \
                   524288, 524288, 524288, 524288, 524288, \
                   524288, 524288, 524288, 524288, 524288}

// ---- compile-time per-level gather body: point-block pb (2048 pts) --------
template<int LV>
__device__ __forceinline__ void gather_body(
    const float* __restrict__ coords,
    const float* __restrict__ tables,
    float2* __restrict__ ws,
    int npts, long long pb, int t)
{
    constexpr int RESI[16] = RESI_LIST;
    constexpr int SIZ[16] = SIZ_LIST;

    const long long base = pb * 2048;
    const float* tab = tables + ((size_t)LV << 20);

    vfloat2 g[8];
#pragma unroll
    for (int j = 0; j < 8; ++j) {
        const long long p = base + j * 256 + t;
        const float cx = coords[3 * p + 0];
        const float cy = coords[3 * p + 1];
        const float cz = coords[3 * p + 2];
        const uint32_t idx = hash_idx(cx, cy, cz, RESI[LV], SIZ[LV]);
        g[j] = *reinterpret_cast<const vfloat2*>(tab + ((size_t)idx << 1));
    }
    float2* wl = ws + (size_t)(LV - 5) * npts + base;
#pragma unroll
    for (int j = 0; j < 8; ++j)   // NT: don't evict the L2-hot table
        __builtin_nontemporal_store(g[j],
            reinterpret_cast<vfloat2*>(wl + j * 256 + t));
}

// ---- Launch A: levels 5..12, one per XCD class (bid%8) --------------------
__global__ __launch_bounds__(TPB) void hashenc_gather_8way(
    const float* __restrict__ coords,
    const float* __restrict__ tables,
    float2* __restrict__ ws,
    int npts)
{
    const int t = threadIdx.x;
    const int c = blockIdx.x & 7;          // XCD class (bid%8 round-robin)
    const long long pb = blockIdx.x >> 3;  // point-block within level
    switch (c) {                           // wave-uniform, compile-time bodies
        case 0: gather_body<5>(coords, tables, ws, npts, pb, t); break;
        case 1: gather_body<6>(coords, tables, ws, npts, pb, t); break;
        case 2: gather_body<7>(coords, tables, ws, npts, pb, t); break;
        case 3: gather_body<8>(coords, tables, ws, npts, pb, t); break;
        case 4: gather_body<9>(coords, tables, ws, npts, pb, t); break;
        case 5: gather_body<10>(coords, tables, ws, npts, pb, t); break;
        case 6: gather_body<11>(coords, tables, ws, npts, pb, t); break;
        case 7: gather_body<12>(coords, tables, ws, npts, pb, t); break;
    }
}

// ---- Launch B: levels 13,14,15 spread {3,3,2} over XCD classes ------------
// class c -> (level, j, m): pb = j + m*k, k = bid>>3; guard pb < npb.
__global__ __launch_bounds__(TPB) void hashenc_gather_tail(
    const float* __restrict__ coords,
    const float* __restrict__ tables,
    float2* __restrict__ ws,
    int npts)
{
    const int t = threadIdx.x;
    const int c = blockIdx.x & 7;
    const long long k = blockIdx.x >> 3;
    const long long npb = npts >> 11;      // npts/2048
    long long pb;
    switch (c) {
        case 0: pb = 0 + 3 * k; if (pb < npb) gather_body<13>(coords, tables, ws, npts, pb, t); break;
        case 1: pb = 1 + 3 * k; if (pb < npb) gather_body<13>(coords, tables, ws, npts, pb, t); break;
        case 2: pb = 2 + 3 * k; if (pb < npb) gather_body<13>(coords, tables, ws, npts, pb, t); break;
        case 3: pb = 0 + 3 * k; if (pb < npb) gather_body<14>(coords, tables, ws, npts, pb, t); break;
        case 4: pb = 1 + 3 * k; if (pb < npb) gather_body<14>(coords, tables, ws, npts, pb, t); break;
        case 5: pb = 2 + 3 * k; if (pb < npb) gather_body<14>(coords, tables, ws, npts, pb, t); break;
        case 6: pb = 0 + 2 * k; if (pb < npb) gather_body<15>(coords, tables, ws, npts, pb, t); break;
        case 7: pb = 1 + 2 * k; if (pb < npb) gather_body<15>(coords, tables, ws, npts, pb, t); break;
    }
}

// ---- Phase 2: coarse gather (levels 0-4, tables 2.47MB = L2-hot)
//      + transpose ws fine levels -> out (N,32) ----------------------------
__global__ __launch_bounds__(TPB) void hashenc_transpose_fused(
    const float* __restrict__ coords,
    const float* __restrict__ tables,
    const float2* __restrict__ ws,
    float* __restrict__ out,
    int npts)
{
    constexpr int RESI[16] = RESI_LIST;
    constexpr int SIZ[16] = SIZ_LIST;

    __shared__ float buf[128 * 33];

    const int t = threadIdx.x;
    const long long pbase = (long long)blockIdx.x * TPB;
    const long long p = pbase + t;

    const float cx = coords[3 * p + 0];
    const float cy = coords[3 * p + 1];
    const float cz = coords[3 * p + 2];

    vfloat2 feat[16];
#pragma unroll
    for (int l = 0; l < 5; ++l) {   // inline coarse gathers (hot tables)
        const uint32_t idx = hash_idx(cx, cy, cz, RESI[l], SIZ[l]);
        feat[l] = *reinterpret_cast<const vfloat2*>(
            tables + ((size_t)l << 20) + ((size_t)idx << 1));
    }
#pragma unroll
    for (int l = 5; l < 16; ++l)    // fine levels from ws (NT streaming)
        feat[l] = __builtin_nontemporal_load(
            reinterpret_cast<const vfloat2*>(ws + (size_t)(l - 5) * npts + p));

    float* oblk = out + pbase * 32;
#pragma unroll
    for (int h = 0; h < 2; ++h) {
        if ((t >> 7) == h) {
            const int r = t & 127;
#pragma unroll
            for (int l = 0; l < 16; ++l) {
                buf[r * 33 + 2 * l + 0] = feat[l].x;
                buf[r * 33 + 2 * l + 1] = feat[l].y;
            }
        }
        __syncthreads();
#pragma unroll
        for (int k = 0; k < 4; ++k) {
            const int f = k * 1024 + t * 4;
            const int row = f >> 5;
            const int col = f & 31;
            const vfloat4 v = *reinterpret_cast<const vfloat4*>(&buf[row * 33 + col]);
            __builtin_nontemporal_store(v,
                reinterpret_cast<vfloat4*>(&oblk[(long long)h * 4096 + f]));
        }
        __syncthreads();
    }
}

// ---- Fallback: R6 single-phase (ws too small / odd N) ---------------------
__global__ __launch_bounds__(TPB) void hashenc_kernel(
    const float* __restrict__ coords,
    const float* __restrict__ tables,
    float* __restrict__ out,
    int npts)
{
    constexpr int RESI[16] = RESI_LIST;
    constexpr int SIZ[16] = SIZ_LIST;

    __shared__ float buf[128 * 33];

    const int t = threadIdx.x;
    const long long pbase = (long long)blockIdx.x * TPB;
    const long long p = pbase + t;

    const float cx = coords[3 * p + 0];
    const float cy = coords[3 * p + 1];
    const float cz = coords[3 * p + 2];

    float2 feat[16];
#pragma unroll
    for (int l = 0; l < 16; ++l) {
        const uint32_t idx = hash_idx(cx, cy, cz, RESI[l], SIZ[l]);
        feat[l] = *reinterpret_cast<const float2*>(
            tables + ((size_t)l << 20) + ((size_t)idx << 1));
    }

    float* oblk = out + pbase * 32;
#pragma unroll
    for (int h = 0; h < 2; ++h) {
        if ((t >> 7) == h) {
            const int r = t & 127;
#pragma unroll
            for (int l = 0; l < 16; ++l) {
                buf[r * 33 + 2 * l + 0] = feat[l].x;
                buf[r * 33 + 2 * l + 1] = feat[l].y;
            }
        }
        __syncthreads();
#pragma unroll
        for (int k = 0; k < 4; ++k) {
            const int f = k * 1024 + t * 4;
            const int row = f >> 5;
            const int col = f & 31;
            const vfloat4 v = *reinterpret_cast<const vfloat4*>(&buf[row * 33 + col]);
            __builtin_nontemporal_store(v,
                reinterpret_cast<vfloat4*>(&oblk[(long long)h * 4096 + f]));
        }
        __syncthreads();
    }
}

extern "C" void kernel_launch(void* const* d_in, const int* in_sizes, int n_in,
                              void* d_out, int out_size, void* d_ws, size_t ws_size,
                              hipStream_t stream)
{
    const float* coords = (const float*)d_in[0];
    const float* tables = (const float*)d_in[1];
    float* out = (float*)d_out;
    const int npts = in_sizes[0] / 3;   // 2^21

    const size_t need = (size_t)11 * (size_t)npts * sizeof(float2);
    if (ws_size >= need && (npts % 2048) == 0) {
        float2* ws = (float2*)d_ws;
        const int npb = npts / 2048;                 // point-blocks per level
        const dim3 gA(npb * 8), gB(((npb + 1) / 2) * 8), b(TPB);
        hipLaunchKernelGGL(hashenc_gather_8way, gA, b, 0, stream,
                           coords, tables, ws, npts);
        hipLaunchKernelGGL(hashenc_gather_tail, gB, b, 0, stream,
                           coords, tables, ws, npts);
        hipLaunchKernelGGL(hashenc_transpose_fused, dim3(npts / TPB), b, 0, stream,
                           coords, tables, (const float2*)d_ws, out, npts);
    } else {
        hipLaunchKernelGGL(hashenc_kernel, dim3(npts / TPB), dim3(TPB), 0, stream,
                           coords, tables, out, npts);
    }
}

// Round 14
// 292.823 us; speedup vs baseline: 14.5254x; 1.0204x over previous
//
#include <hip/hip_runtime.h>
#include <stdint.h>

// MultiResolutionHashEncoding — R14: single balanced gather launch.
//
// R13 (one-level-per-XCD, 2 launches): 299us. Launch-count cut 6->2 saved
//   only 5us -> gather is at per-XCD L2 random-request service rate
//   (~2-3M line-req/XCD @ ~6-10 req/cyc). Remaining waste: A->B boundary
//   ramp/drain + launch B imbalance (level-15 classes do 1.5x work).
// R14: ONE gather launch. Class c (bid%8 -> XCD) runs primary level 5+c
//   for all npb point-blocks, then slice [c*per_class,(c+1)*per_class) of
//   the 3*npb tail units (levels 13/14/15). Per-XCD work balanced at
//   2.75M requests; levels walked sequentially within an XCD (block start
//   order ~ bid order) so L2 holds one 4MB table at a time.
// Floor model: request service ~170us + transpose ~85-95us => ~255-265us
//   structural; if this round gains <10us we are AT the floor.

#define TPB 256

typedef float vfloat4 __attribute__((ext_vector_type(4)));
typedef float vfloat2 __attribute__((ext_vector_type(2)));

__device__ __forceinline__ uint32_t hash_idx(float cx, float cy, float cz,
                                             int resi, int siz)
{
    const float rf = (float)resi;
    const int x = (int)floorf(cx * rf);
    const int y = (int)floorf(cy * rf);
    const int z = (int)floorf(cz * rf);
    // int32 wraparound multiplies + xor (uint32 = UB-free)
    const uint32_t h = (uint32_t)x * 73856093u
                     ^ (uint32_t)y * 19349663u
                     ^ (uint32_t)z * 83492791u;
    const int32_t hs = (int32_t)h;
    if (siz == (1 << 19)) {
        // numpy abs(INT_MIN)=INT_MIN; python-mod 2^19 == mask
        const uint32_t a = (hs < 0) ? (0u - h) : h;
        return a & 0x7FFFFu;
    } else {
        int32_t a = (hs < 0) ? (int32_t)(0u - h) : hs;
        int32_t r = a % siz;          // compile-time divisor -> magic mul
        if (r < 0) r += siz;
        return (uint32_t)r;
    }
}

#define RESI_LIST {16, 22, 30, 42, 58, 80, 111, 153, \
                   212, 294, 406, 561, 776, 1072, 1482, 2048}
#define SIZ_LIST  {4096, 10648, 27000, 74088, 195112, 512000, \
                   524288, 524288, 524288, 524288, 524288, \
                   524288, 524288, 524288, 524288, 524288}

// ---- compile-time per-level gather body: point-block pb (2048 pts) --------
template<int LV>
__device__ __forceinline__ void gather_body(
    const float* __restrict__ coords,
    const float* __restrict__ tables,
    float2* __restrict__ ws,
    int npts, long long pb, int t)
{
    constexpr int RESI[16] = RESI_LIST;
    constexpr int SIZ[16] = SIZ_LIST;

    const long long base = pb * 2048;
    const float* tab = tables + ((size_t)LV << 20);

    vfloat2 g[8];
#pragma unroll
    for (int j = 0; j < 8; ++j) {
        const long long p = base + j * 256 + t;
        const float cx = coords[3 * p + 0];
        const float cy = coords[3 * p + 1];
        const float cz = coords[3 * p + 2];
        const uint32_t idx = hash_idx(cx, cy, cz, RESI[LV], SIZ[LV]);
        g[j] = *reinterpret_cast<const vfloat2*>(tab + ((size_t)idx << 1));
    }
    float2* wl = ws + (size_t)(LV - 5) * npts + base;
#pragma unroll
    for (int j = 0; j < 8; ++j)   // NT: don't evict the L2-hot table
        __builtin_nontemporal_store(g[j],
            reinterpret_cast<vfloat2*>(wl + j * 256 + t));
}

// ---- single balanced gather launch ----------------------------------------
// class c = bid%8 (XCD): k<npb -> primary level 5+c, pb=k;
// else tail unit ti = c*per_class + (k-npb) in [0,3*npb):
//   level = 13 + ti/npb, pb = ti%npb. Sequential per XCD.
__global__ __launch_bounds__(TPB) void hashenc_gather_merged(
    const float* __restrict__ coords,
    const float* __restrict__ tables,
    float2* __restrict__ ws,
    int npts)
{
    const int t = threadIdx.x;
    const int c = blockIdx.x & 7;
    const long long k = blockIdx.x >> 3;
    const long long npb = (long long)npts >> 11;   // npts/2048

    if (k < npb) {
        switch (c) {   // wave-uniform, compile-time bodies
            case 0: gather_body<5>(coords, tables, ws, npts, k, t); break;
            case 1: gather_body<6>(coords, tables, ws, npts, k, t); break;
            case 2: gather_body<7>(coords, tables, ws, npts, k, t); break;
            case 3: gather_body<8>(coords, tables, ws, npts, k, t); break;
            case 4: gather_body<9>(coords, tables, ws, npts, k, t); break;
            case 5: gather_body<10>(coords, tables, ws, npts, k, t); break;
            case 6: gather_body<11>(coords, tables, ws, npts, k, t); break;
            case 7: gather_body<12>(coords, tables, ws, npts, k, t); break;
        }
    } else {
        const long long per_class = (3 * npb + 7) >> 3;
        const long long ti = (long long)c * per_class + (k - npb);
        if (ti < 3 * npb) {
            const long long pb = ti % npb;
            switch ((int)(ti / npb)) {
                case 0: gather_body<13>(coords, tables, ws, npts, pb, t); break;
                case 1: gather_body<14>(coords, tables, ws, npts, pb, t); break;
                case 2: gather_body<15>(coords, tables, ws, npts, pb, t); break;
            }
        }
    }
}

// ---- Phase 2: coarse gather (levels 0-4, tables 2.47MB = L2-hot)
//      + transpose ws fine levels -> out (N,32) ----------------------------
__global__ __launch_bounds__(TPB) void hashenc_transpose_fused(
    const float* __restrict__ coords,
    const float* __restrict__ tables,
    const float2* __restrict__ ws,
    float* __restrict__ out,
    int npts)
{
    constexpr int RESI[16] = RESI_LIST;
    constexpr int SIZ[16] = SIZ_LIST;

    __shared__ float buf[128 * 33];

    const int t = threadIdx.x;
    const long long pbase = (long long)blockIdx.x * TPB;
    const long long p = pbase + t;

    const float cx = coords[3 * p + 0];
    const float cy = coords[3 * p + 1];
    const float cz = coords[3 * p + 2];

    vfloat2 feat[16];
#pragma unroll
    for (int l = 0; l < 5; ++l) {   // inline coarse gathers (hot tables)
        const uint32_t idx = hash_idx(cx, cy, cz, RESI[l], SIZ[l]);
        feat[l] = *reinterpret_cast<const vfloat2*>(
            tables + ((size_t)l << 20) + ((size_t)idx << 1));
    }
#pragma unroll
    for (int l = 5; l < 16; ++l)    // fine levels from ws (NT streaming)
        feat[l] = __builtin_nontemporal_load(
            reinterpret_cast<const vfloat2*>(ws + (size_t)(l - 5) * npts + p));

    float* oblk = out + pbase * 32;
#pragma unroll
    for (int h = 0; h < 2; ++h) {
        if ((t >> 7) == h) {
            const int r = t & 127;
#pragma unroll
            for (int l = 0; l < 16; ++l) {
                buf[r * 33 + 2 * l + 0] = feat[l].x;
                buf[r * 33 + 2 * l + 1] = feat[l].y;
            }
        }
        __syncthreads();
#pragma unroll
        for (int k = 0; k < 4; ++k) {
            const int f = k * 1024 + t * 4;
            const int row = f >> 5;
            const int col = f & 31;
            const vfloat4 v = *reinterpret_cast<const vfloat4*>(&buf[row * 33 + col]);
            __builtin_nontemporal_store(v,
                reinterpret_cast<vfloat4*>(&oblk[(long long)h * 4096 + f]));
        }
        __syncthreads();
    }
}

// ---- Fallback: R6 single-phase (ws too small / odd N) ---------------------
__global__ __launch_bounds__(TPB) void hashenc_kernel(
    const float* __restrict__ coords,
    const float* __restrict__ tables,
    float* __restrict__ out,
    int npts)
{
    constexpr int RESI[16] = RESI_LIST;
    constexpr int SIZ[16] = SIZ_LIST;

    __shared__ float buf[128 * 33];

    const int t = threadIdx.x;
    const long long pbase = (long long)blockIdx.x * TPB;
    const long long p = pbase + t;

    const float cx = coords[3 * p + 0];
    const float cy = coords[3 * p + 1];
    const float cz = coords[3 * p + 2];

    float2 feat[16];
#pragma unroll
    for (int l = 0; l < 16; ++l) {
        const uint32_t idx = hash_idx(cx, cy, cz, RESI[l], SIZ[l]);
        feat[l] = *reinterpret_cast<const float2*>(
            tables + ((size_t)l << 20) + ((size_t)idx << 1));
    }

    float* oblk = out + pbase * 32;
#pragma unroll
    for (int h = 0; h < 2; ++h) {
        if ((t >> 7) == h) {
            const int r = t & 127;
#pragma unroll
            for (int l = 0; l < 16; ++l) {
                buf[r * 33 + 2 * l + 0] = feat[l].x;
                buf[r * 33 + 2 * l + 1] = feat[l].y;
            }
        }
        __syncthreads();
#pragma unroll
        for (int k = 0; k < 4; ++k) {
            const int f = k * 1024 + t * 4;
            const int row = f >> 5;
            const int col = f & 31;
            const vfloat4 v = *reinterpret_cast<const vfloat4*>(&buf[row * 33 + col]);
            __builtin_nontemporal_store(v,
                reinterpret_cast<vfloat4*>(&oblk[(long long)h * 4096 + f]));
        }
        __syncthreads();
    }
}

extern "C" void kernel_launch(void* const* d_in, const int* in_sizes, int n_in,
                              void* d_out, int out_size, void* d_ws, size_t ws_size,
                              hipStream_t stream)
{
    const float* coords = (const float*)d_in[0];
    const float* tables = (const float*)d_in[1];
    float* out = (float*)d_out;
    const int npts = in_sizes[0] / 3;   // 2^21

    const size_t need = (size_t)11 * (size_t)npts * sizeof(float2);
    if (ws_size >= need && (npts % 2048) == 0) {
        float2* ws = (float2*)d_ws;
        const long long npb = npts / 2048;
        const long long per_class = (3 * npb + 7) / 8;
        const dim3 g((unsigned)(8 * (npb + per_class))), b(TPB);
        hipLaunchKernelGGL(hashenc_gather_merged, g, b, 0, stream,
                           coords, tables, ws, npts);
        hipLaunchKernelGGL(hashenc_transpose_fused, dim3(npts / TPB), b, 0, stream,
                           coords, tables, (const float2*)d_ws, out, npts);
    } else {
        hipLaunchKernelGGL(hashenc_kernel, dim3(npts / TPB), dim3(TPB), 0, stream,
                           coords, tables, out, npts);
    }
}